// Round 4
// baseline (75.474 us; speedup 1.0000x reference)
//
#include <hip/hip_runtime.h>

#define K_CODES 32768
#define N_PTS   8192
#define PPT     2                    // points per thread in k_dist
#define TPB     256
#define PTS_PER_BLK (TPB * PPT)      // 512
#define NPB     (N_PTS / PTS_PER_BLK) // 16

typedef float v2f __attribute__((ext_vector_type(2)));

// Packed fp32 (IEEE per 32-bit half) — bit-identical to scalar chain (verified R1-R3)
__device__ __forceinline__ v2f pk_mul(v2f a, v2f b) {
    v2f d; asm("v_pk_mul_f32 %0, %1, %2" : "=v"(d) : "v"(a), "v"(b)); return d;
}
__device__ __forceinline__ v2f pk_fma(v2f a, v2f b, v2f c) {
    v2f d; asm("v_pk_fma_f32 %0, %1, %2, %3" : "=v"(d) : "v"(a), "v"(b), "v"(c)); return d;
}
__device__ __forceinline__ v2f pk_add(v2f a, v2f b) {
    v2f d; asm("v_pk_add_f32 %0, %1, %2" : "=v"(d) : "v"(a), "v"(b)); return d;
}
__device__ __forceinline__ float min3f(float a, float b, float c) {
    float d; asm("v_min3_f32 %0, %1, %2, %3" : "=v"(d) : "v"(a), "v"(b), "v"(c)); return d;
}

// ---------------- K1: partial argmin over one code chunk, 2 points per thread
template<int CHUNK>
__global__ __launch_bounds__(256) void k_dist(const float* __restrict__ x,
                                              const float* __restrict__ E,
                                              float2* __restrict__ dk) {
#pragma clang fp contract(off)
    __shared__ __align__(16) float lds[5 * CHUNK];
    float* exL = lds;
    float* eyL = lds + CHUNK;
    float* ezL = lds + 2 * CHUNK;
    float* ewL = lds + 3 * CHUNK;
    float* bL  = lds + 4 * CHUNK;

    const int chunk = blockIdx.x;
    const int pblk  = blockIdx.y;
    const int tid   = threadIdx.x;
    const int kbase = chunk * CHUNK;

    // Stage SoA + fused bnorm (squares individually rounded, sequential adds)
    for (int i = tid; i < CHUNK; i += TPB) {
        float4 e = ((const float4*)E)[kbase + i];
        exL[i] = e.x; eyL[i] = e.y; ezL[i] = e.z; ewL[i] = e.w;
        bL[i]  = ((e.x * e.x + e.y * e.y) + e.z * e.z) + e.w * e.w;
    }
    __syncthreads();

    // two points: p0 = base+tid, p1 = p0+256
    const int p0 = pblk * PTS_PER_BLK + tid;
    const int p1 = p0 + TPB;
    const int t0 = p0 >> 12, s0 = p0 & 4095;
    const int t1 = p1 >> 12, s1 = p1 & 4095;
    const int xb0 = t0 * 16384 + s0;
    const int xb1 = t1 * 16384 + s1;

    const float x00 = x[xb0], x01 = x[xb0 + 4096], x02 = x[xb0 + 8192], x03 = x[xb0 + 12288];
    const float x10 = x[xb1], x11 = x[xb1 + 4096], x12 = x[xb1 + 8192], x13 = x[xb1 + 12288];
    const float a0 = ((x00 * x00 + x01 * x01) + x02 * x02) + x03 * x03;
    const float a1 = ((x10 * x10 + x11 * x11) + x12 * x12) + x13 * x13;

    const v2f X00 = {x00, x00}, X01 = {x01, x01}, X02 = {x02, x02}, X03 = {x03, x03};
    const v2f X10 = {x10, x10}, X11 = {x11, x11}, X12 = {x12, x12}, X13 = {x13, x13};
    const v2f A0 = {a0, a0}, A1 = {a1, a1};
    const v2f M2 = {-2.0f, -2.0f};

    float bd0 = 3.402823466e38f, bd1 = 3.402823466e38f;
    int   bk0 = 0, bk1 = 0;

#pragma unroll 2
    for (int q = 0; q < CHUNK / 4; ++q) {      // 4 codes x 2 points per iter
        float4 vx = *(const float4*)(exL + 4 * q);
        float4 vy = *(const float4*)(eyL + 4 * q);
        float4 vz = *(const float4*)(ezL + 4 * q);
        float4 vw = *(const float4*)(ewL + 4 * q);
        float4 vb = *(const float4*)(bL  + 4 * q);

        v2f ex0 = {vx.x, vx.y}, ex1 = {vx.z, vx.w};
        v2f ey0 = {vy.x, vy.y}, ey1 = {vy.z, vy.w};
        v2f ez0 = {vz.x, vz.y}, ez1 = {vz.z, vz.w};
        v2f ew0 = {vw.x, vw.y}, ew1 = {vw.z, vw.w};
        v2f b0  = {vb.x, vb.y}, b1  = {vb.z, vb.w};

        const int kq = kbase + 4 * q;

        // ---- point 0
        v2f m00 = pk_fma(X03, ew0, pk_fma(X02, ez0, pk_fma(X01, ey0, pk_mul(X00, ex0))));
        v2f m01 = pk_fma(X03, ew1, pk_fma(X02, ez1, pk_fma(X01, ey1, pk_mul(X00, ex1))));
        v2f d00 = pk_fma(M2, m00, pk_add(A0, b0));
        v2f d01 = pk_fma(M2, m01, pk_add(A0, b1));
        {
            float bd4 = min3f(min3f(bd0, d00.x, d00.y), d01.x, d01.y);
            int sel = (d01.x == bd4) ? 2 : 3;
            sel = (d00.y == bd4) ? 1 : sel;
            sel = (d00.x == bd4) ? 0 : sel;
            bool imp = (bd4 != bd0);           // tie with old bd -> keep earlier bk
            bk0 = imp ? (kq + sel) : bk0;
            bd0 = bd4;
        }
        // ---- point 1
        v2f m10 = pk_fma(X13, ew0, pk_fma(X12, ez0, pk_fma(X11, ey0, pk_mul(X10, ex0))));
        v2f m11 = pk_fma(X13, ew1, pk_fma(X12, ez1, pk_fma(X11, ey1, pk_mul(X10, ex1))));
        v2f d10 = pk_fma(M2, m10, pk_add(A1, b0));
        v2f d11 = pk_fma(M2, m11, pk_add(A1, b1));
        {
            float bd4 = min3f(min3f(bd1, d10.x, d10.y), d11.x, d11.y);
            int sel = (d11.x == bd4) ? 2 : 3;
            sel = (d10.y == bd4) ? 1 : sel;
            sel = (d10.x == bd4) ? 0 : sel;
            bool imp = (bd4 != bd1);
            bk1 = imp ? (kq + sel) : bk1;
            bd1 = bd4;
        }
    }
    dk[chunk * N_PTS + p0] = make_float2(bd0, __int_as_float(bk0));
    dk[chunk * N_PTS + p1] = make_float2(bd1, __int_as_float(bk1));
}

// ---------------- K2: merge chunks, gather, z_q_st, per-block loss partial
__global__ __launch_bounds__(64) void k_final(const float* __restrict__ x,
                                              const float* __restrict__ E,
                                              const float2* __restrict__ dk,
                                              float* __restrict__ out,
                                              double* __restrict__ partials,
                                              int nc) {
#pragma clang fp contract(off)
    const int tid = threadIdx.x;
    const int p   = blockIdx.x * 64 + tid;     // 128 blocks x 64 threads
    const int t   = p >> 12;
    const int s   = p & 4095;

    float bd = 3.402823466e38f;
    int   bk = 0;
    for (int c = 0; c < nc; ++c) {             // increasing k ranges
        float2 v = dk[c * N_PTS + p];
        if (v.x < bd) { bd = v.x; bk = __float_as_int(v.y); }  // strict <
    }

    float4 e = ((const float4*)E)[bk];
    float ev[4] = {e.x, e.y, e.z, e.w};
    double ls = 0.0;
    const int xb = t * 16384 + s;
    for (int ch = 0; ch < 4; ++ch) {
        int idx = xb + ch * 4096;
        float xv   = x[idx];
        float diff = ev[ch] - xv;              // fl(z_q - x)
        float sq   = diff * diff;              // fl(diff^2)
        out[idx]   = xv + diff;                // z_q_st = fl(x + fl(z_q - x))
        ls += (double)sq;
    }
    out[32769 + p] = (float)bk;                // codes as float

    for (int o = 32; o > 0; o >>= 1) ls += __shfl_down(ls, o);
    if (tid == 0) partials[blockIdx.x] = ls;
}

// ---------------- K3: finalize qloss
__global__ void k_loss(const double* __restrict__ partials,
                       float* __restrict__ out) {
#pragma clang fp contract(off)
    if (threadIdx.x == 0 && blockIdx.x == 0) {
        double sum = 0.0;
        for (int i = 0; i < 128; ++i) sum += partials[i];
        float mu = (float)(sum * (1.0 / 32768.0));   // /32768 exact
        float q  = mu + 0.1f * mu;                   // mean1 + BETA*mean2
        out[32768] = q;
    }
}

extern "C" void kernel_launch(void* const* d_in, const int* in_sizes, int n_in,
                              void* d_out, int out_size, void* d_ws, size_t ws_size,
                              hipStream_t stream) {
    const float* x = (const float*)d_in[0];   // (1,2,4,64,64)
    const float* E = (const float*)d_in[1];   // (32768,4)
    float* out = (float*)d_out;               // 40961 floats

    char* ws = (char*)d_ws;
    double* partials = (double*)ws;                    // 1 KB
    float2* dk       = (float2*)(ws + 1024);

    // NC=64 needs 64*8192*8B = 4MB of ws; fall back to NC=32 (2MB, proven) if small
    const size_t need64 = 1024 + (size_t)64 * N_PTS * 8;
    if (ws_size >= need64) {
        dim3 g(64, NPB);
        k_dist<512><<<g, TPB, 0, stream>>>(x, E, dk);
        k_final<<<N_PTS / 64, 64, 0, stream>>>(x, E, dk, out, partials, 64);
    } else {
        dim3 g(32, NPB);
        k_dist<1024><<<g, TPB, 0, stream>>>(x, E, dk);
        k_final<<<N_PTS / 64, 64, 0, stream>>>(x, E, dk, out, partials, 32);
    }
    k_loss<<<1, 64, 0, stream>>>(partials, out);
}